// Round 2
// baseline (555.558 us; speedup 1.0000x reference)
//
#include <hip/hip_runtime.h>
#include <hip/hip_bf16.h>

#define B_ 8
#define D_ 128
#define NH 8
#define L_ 1024
#define DK 16

// ---------------------------------------------------------------------------
// Kernel A: QKV projection.  grid (L/256, B*Nh, 3), block 256.
// Q[bh,k,l] = sum_d W[h,b,k,d] * x[b,d,l]
// ---------------------------------------------------------------------------
__global__ void proj_kernel(const float* __restrict__ x,
                            const float* __restrict__ Wq,
                            const float* __restrict__ Wk,
                            const float* __restrict__ Wv,
                            float* __restrict__ Q,
                            float* __restrict__ K,
                            float* __restrict__ V) {
    const int l  = blockIdx.x * 256 + threadIdx.x;
    const int bh = blockIdx.y;          // bh = b*NH + h
    const int b  = bh >> 3;             // / NH
    const int h  = bh & 7;              // % NH
    const int which = blockIdx.z;

    const float* W = (which == 0) ? Wq : (which == 1) ? Wk : Wv;
    float*       O = (which == 0) ? Q  : (which == 1) ? K  : V;

    // W layout: (Nh, B, Dk, D) -> ((h*B + b)*DK + k)*D_ + d
    __shared__ float Ws[DK * D_];       // 16*128 fp32 = 8 KB
    const float* Wp = W + ((size_t)(h * B_ + b)) * (DK * D_);
    for (int i = threadIdx.x; i < DK * D_; i += 256)
        Ws[i] = Wp[i];
    __syncthreads();

    float acc[DK];
#pragma unroll
    for (int k = 0; k < DK; ++k) acc[k] = 0.f;

    const float* xp = x + (size_t)b * D_ * L_ + l;
    for (int d = 0; d < D_; ++d) {
        float xv = xp[(size_t)d * L_];          // coalesced across threads
#pragma unroll
        for (int k = 0; k < DK; ++k)
            acc[k] = fmaf(Ws[k * D_ + d], xv, acc[k]);  // LDS broadcast
    }

    float* Op = O + ((size_t)bh * DK) * L_ + l;
#pragma unroll
    for (int k = 0; k < DK; ++k)
        Op[(size_t)k * L_] = acc[k];
}

// ---------------------------------------------------------------------------
// Kernel B: attention with online softmax over the i axis (column-wise
// softmax of S).  head[:,j] = sum_i softmax_i(K[:,j]·Q[:,i]) * V[:,i]
// grid (L/256, B*Nh), block 256; one thread per output column j.
// ---------------------------------------------------------------------------
#define CHUNK 128
__global__ void attn_kernel(const float* __restrict__ Q,
                            const float* __restrict__ K,
                            const float* __restrict__ V,
                            float* __restrict__ head) {
    const int j  = blockIdx.x * 256 + threadIdx.x;
    const int bh = blockIdx.y;

    const float* Qp = Q + (size_t)bh * DK * L_;
    const float* Kp = K + (size_t)bh * DK * L_;
    const float* Vp = V + (size_t)bh * DK * L_;

    float kv[DK];
#pragma unroll
    for (int k = 0; k < DK; ++k)
        kv[k] = Kp[(size_t)k * L_ + j] * 0.25f;   // scale = 1/sqrt(16)

    __shared__ float Qs[DK][CHUNK];   // 8 KB
    __shared__ float Vs[DK][CHUNK];   // 8 KB

    float m = -INFINITY, lsum = 0.f;
    float acc[DK];
#pragma unroll
    for (int k = 0; k < DK; ++k) acc[k] = 0.f;

    for (int i0 = 0; i0 < L_; i0 += CHUNK) {
        __syncthreads();
        for (int t = threadIdx.x; t < DK * CHUNK; t += 256) {
            int k  = t / CHUNK;
            int ii = t % CHUNK;
            Qs[k][ii] = Qp[(size_t)k * L_ + i0 + ii];
            Vs[k][ii] = Vp[(size_t)k * L_ + i0 + ii];
        }
        __syncthreads();

        for (int ii = 0; ii < CHUNK; ++ii) {
            float s = 0.f;
#pragma unroll
            for (int k = 0; k < DK; ++k)
                s = fmaf(Qs[k][ii], kv[k], s);    // LDS broadcast reads

            float mn = fmaxf(m, s);
            float alpha = __expf(m - mn);         // first iter: exp(-inf)=0
            float p     = __expf(s - mn);
            lsum = lsum * alpha + p;
#pragma unroll
            for (int k = 0; k < DK; ++k)
                acc[k] = fmaf(acc[k], alpha, p * Vs[k][ii]);
            m = mn;
        }
    }

    const float inv = 1.f / lsum;
    float* Hp = head + (size_t)bh * DK * L_ + j;
#pragma unroll
    for (int v = 0; v < DK; ++v)
        Hp[(size_t)v * L_] = acc[v] * inv;
}

// ---------------------------------------------------------------------------
// Kernel C: out[b,o,l] = sum_d Wo[b,o,d] * head[b,d,l]  (output fp32)
// grid (L/128, B), block 256.  head tile (128 x 128 fp32 = 64 KB) in LDS.
// ---------------------------------------------------------------------------
__global__ void out_kernel(const float* __restrict__ head,
                           const float* __restrict__ Wo,
                           float* __restrict__ out) {
    const int b  = blockIdx.y;
    const int l0 = blockIdx.x * 128;

    __shared__ float Hs[128][128];    // 64 KB
    for (int t = threadIdx.x; t < 128 * 128; t += 256) {
        int d  = t >> 7;
        int ll = t & 127;
        Hs[d][ll] = head[((size_t)b * 128 + d) * L_ + l0 + ll];
    }
    __syncthreads();

    const float* Wb = Wo + (size_t)b * 128 * 128;
    for (int c = 0; c < 64; ++c) {
        int e  = c * 256 + threadIdx.x;
        int o  = e >> 7;
        int ll = e & 127;
        float s = 0.f;
        const float* Wrow = Wb + (size_t)o * 128;
        for (int d = 0; d < 128; ++d)
            s = fmaf(Wrow[d], Hs[d][ll], s);
        out[((size_t)b * 128 + o) * L_ + l0 + ll] = s;
    }
}

// ---------------------------------------------------------------------------
extern "C" void kernel_launch(void* const* d_in, const int* in_sizes, int n_in,
                              void* d_out, int out_size, void* d_ws, size_t ws_size,
                              hipStream_t stream) {
    const float* x  = (const float*)d_in[0];
    const float* Wq = (const float*)d_in[1];
    const float* Wk = (const float*)d_in[2];
    const float* Wv = (const float*)d_in[3];
    const float* Wo = (const float*)d_in[4];
    float* out = (float*)d_out;

    // fp32 workspace: Q,K,V,head each B*Nh*Dk*L = 1,048,576 floats (4 MB)
    const size_t SEG = (size_t)B_ * NH * DK * L_;
    float* Q    = (float*)d_ws;
    float* K    = Q + SEG;
    float* V    = K + SEG;
    float* head = V + SEG;

    proj_kernel<<<dim3(L_ / 256, B_ * NH, 3), 256, 0, stream>>>(x, Wq, Wk, Wv, Q, K, V);
    attn_kernel<<<dim3(L_ / 256, B_ * NH), 256, 0, stream>>>(Q, K, V, head);
    out_kernel<<<dim3(L_ / 128, B_), 256, 0, stream>>>(head, Wo, out);
}

// Round 3
// 218.264 us; speedup vs baseline: 2.5453x; 2.5453x over previous
//
#include <hip/hip_runtime.h>
#include <hip/hip_bf16.h>

#define B_ 8
#define D_ 128
#define NH 8
#define L_ 1024
#define DK 16

// ---------------------------------------------------------------------------
// Kernel A: QKV projection.  grid (L/256, B*Nh, 3), block 256.
// Q[bh,k,l] = sum_d W[h,b,k,d] * x[b,d,l]
// LDS tile transposed: Ws[d][k] (pad 20) so inner loop reads 4x float4
// (broadcast ds_read_b128, conflict-free).
// ---------------------------------------------------------------------------
__global__ __launch_bounds__(256)
void proj_kernel(const float* __restrict__ x,
                 const float* __restrict__ Wq,
                 const float* __restrict__ Wk,
                 const float* __restrict__ Wv,
                 float* __restrict__ Q,
                 float* __restrict__ K,
                 float* __restrict__ V) {
    const int l  = blockIdx.x * 256 + threadIdx.x;
    const int bh = blockIdx.y;          // bh = b*NH + h
    const int b  = bh >> 3;
    const int h  = bh & 7;
    const int which = blockIdx.z;

    const float* W = (which == 0) ? Wq : (which == 1) ? Wk : Wv;
    float*       O = (which == 0) ? Q  : (which == 1) ? K  : V;

    // W layout: (Nh, B, Dk, D) -> ((h*B + b)*DK + k)*D_ + d
    __shared__ float Ws[D_][20];        // [d][k], rows 80 B (16B-aligned)
    const float* Wp = W + ((size_t)(h * B_ + b)) * (DK * D_);
    for (int t = threadIdx.x; t < DK * D_; t += 256) {
        int d = t & 127;                // consecutive lanes -> consecutive d
        int k = t >> 7;
        Ws[d][k] = Wp[k * D_ + d];      // global coalesced in d
    }
    __syncthreads();

    float acc[DK];
#pragma unroll
    for (int k = 0; k < DK; ++k) acc[k] = 0.f;

    const float* xp = x + (size_t)b * D_ * L_ + l;
    for (int d = 0; d < D_; ++d) {
        float xv = xp[(size_t)d * L_];  // coalesced across threads
        const float4* w4 = (const float4*)(&Ws[d][0]);
        float4 w0 = w4[0], w1 = w4[1], w2 = w4[2], w3 = w4[3];
        acc[0]  = fmaf(w0.x, xv, acc[0]);  acc[1]  = fmaf(w0.y, xv, acc[1]);
        acc[2]  = fmaf(w0.z, xv, acc[2]);  acc[3]  = fmaf(w0.w, xv, acc[3]);
        acc[4]  = fmaf(w1.x, xv, acc[4]);  acc[5]  = fmaf(w1.y, xv, acc[5]);
        acc[6]  = fmaf(w1.z, xv, acc[6]);  acc[7]  = fmaf(w1.w, xv, acc[7]);
        acc[8]  = fmaf(w2.x, xv, acc[8]);  acc[9]  = fmaf(w2.y, xv, acc[9]);
        acc[10] = fmaf(w2.z, xv, acc[10]); acc[11] = fmaf(w2.w, xv, acc[11]);
        acc[12] = fmaf(w3.x, xv, acc[12]); acc[13] = fmaf(w3.y, xv, acc[13]);
        acc[14] = fmaf(w3.z, xv, acc[14]); acc[15] = fmaf(w3.w, xv, acc[15]);
    }

    float* Op = O + ((size_t)bh * DK) * L_ + l;
#pragma unroll
    for (int k = 0; k < DK; ++k)
        Op[(size_t)k * L_] = acc[k];
}

// ---------------------------------------------------------------------------
// Kernel B: attention, softmax over i (column softmax of S).
// head[:,j] = sum_i exp(K[:,j]·Q[:,i]*scale) * V[:,i] / lsum
// No max-subtraction: |s| is bounded (~20 << 88), fp32 exp cannot overflow.
// grid (L/256, B*Nh), block 256; one thread per output column j.
// LDS tiles transposed [ii][k] (pad 20) -> 8 broadcast ds_read_b128 per i.
// ---------------------------------------------------------------------------
#define CHUNK 128
__global__ __launch_bounds__(256)
void attn_kernel(const float* __restrict__ Q,
                 const float* __restrict__ K,
                 const float* __restrict__ V,
                 float* __restrict__ head) {
    const int j  = blockIdx.x * 256 + threadIdx.x;
    const int bh = blockIdx.y;

    const float* Qp = Q + (size_t)bh * DK * L_;
    const float* Kp = K + (size_t)bh * DK * L_;
    const float* Vp = V + (size_t)bh * DK * L_;

    float kv[DK];
#pragma unroll
    for (int k = 0; k < DK; ++k)
        kv[k] = Kp[(size_t)k * L_ + j] * 0.25f;   // scale = 1/sqrt(16)

    __shared__ float Qs[CHUNK][20];   // 10 KB, rows 80 B (16B-aligned)
    __shared__ float Vs[CHUNK][20];   // 10 KB

    float lsum = 0.f;
    float acc[DK];
#pragma unroll
    for (int k = 0; k < DK; ++k) acc[k] = 0.f;

    for (int i0 = 0; i0 < L_; i0 += CHUNK) {
        __syncthreads();
        for (int t = threadIdx.x; t < DK * CHUNK; t += 256) {
            int ii = t & (CHUNK - 1);   // consecutive lanes -> consecutive ii
            int k  = t >> 7;
            Qs[ii][k] = Qp[(size_t)k * L_ + i0 + ii];  // coalesced
            Vs[ii][k] = Vp[(size_t)k * L_ + i0 + ii];
        }
        __syncthreads();

        for (int ii = 0; ii < CHUNK; ++ii) {
            const float4* q4 = (const float4*)(&Qs[ii][0]);
            float4 q0 = q4[0], q1 = q4[1], q2 = q4[2], q3 = q4[3];
            // 4 partial dot products to shorten the dependent-fma chain
            float s0 = q0.x * kv[0];
            float s1 = q1.x * kv[4];
            float s2 = q2.x * kv[8];
            float s3 = q3.x * kv[12];
            s0 = fmaf(q0.y, kv[1],  s0); s0 = fmaf(q0.z, kv[2],  s0); s0 = fmaf(q0.w, kv[3],  s0);
            s1 = fmaf(q1.y, kv[5],  s1); s1 = fmaf(q1.z, kv[6],  s1); s1 = fmaf(q1.w, kv[7],  s1);
            s2 = fmaf(q2.y, kv[9],  s2); s2 = fmaf(q2.z, kv[10], s2); s2 = fmaf(q2.w, kv[11], s2);
            s3 = fmaf(q3.y, kv[13], s3); s3 = fmaf(q3.z, kv[14], s3); s3 = fmaf(q3.w, kv[15], s3);
            float s = (s0 + s1) + (s2 + s3);

            float p = __expf(s);
            lsum += p;

            const float4* v4 = (const float4*)(&Vs[ii][0]);
            float4 v0 = v4[0], v1 = v4[1], v2 = v4[2], v3 = v4[3];
            acc[0]  = fmaf(p, v0.x, acc[0]);  acc[1]  = fmaf(p, v0.y, acc[1]);
            acc[2]  = fmaf(p, v0.z, acc[2]);  acc[3]  = fmaf(p, v0.w, acc[3]);
            acc[4]  = fmaf(p, v1.x, acc[4]);  acc[5]  = fmaf(p, v1.y, acc[5]);
            acc[6]  = fmaf(p, v1.z, acc[6]);  acc[7]  = fmaf(p, v1.w, acc[7]);
            acc[8]  = fmaf(p, v2.x, acc[8]);  acc[9]  = fmaf(p, v2.y, acc[9]);
            acc[10] = fmaf(p, v2.z, acc[10]); acc[11] = fmaf(p, v2.w, acc[11]);
            acc[12] = fmaf(p, v3.x, acc[12]); acc[13] = fmaf(p, v3.y, acc[13]);
            acc[14] = fmaf(p, v3.z, acc[14]); acc[15] = fmaf(p, v3.w, acc[15]);
        }
    }

    const float inv = 1.f / lsum;
    float* Hp = head + (size_t)bh * DK * L_ + j;
#pragma unroll
    for (int v = 0; v < DK; ++v)
        Hp[(size_t)v * L_] = acc[v] * inv;
}

// ---------------------------------------------------------------------------
// Kernel C: out[b,o,l] = sum_d Wo[b,o,d] * head[b,d,l]
// Same shape as proj: grid (L/256, 8 o-chunks * B), block 256, thread per l,
// 16 output rows per block, Wo tile transposed [d][oo] in LDS.
// ---------------------------------------------------------------------------
__global__ __launch_bounds__(256)
void out_kernel(const float* __restrict__ head,
                const float* __restrict__ Wo,
                float* __restrict__ out) {
    const int l  = blockIdx.x * 256 + threadIdx.x;
    const int oc = blockIdx.y & 7;      // o-chunk
    const int b  = blockIdx.y >> 3;
    const int o0 = oc * 16;

    __shared__ float Ws[D_][20];        // [d][oo]
    const float* Wb = Wo + (size_t)b * D_ * D_;
    for (int t = threadIdx.x; t < 16 * D_; t += 256) {
        int d  = t & 127;
        int oo = t >> 7;
        Ws[d][oo] = Wb[(size_t)(o0 + oo) * D_ + d];  // coalesced in d
    }
    __syncthreads();

    float acc[16];
#pragma unroll
    for (int k = 0; k < 16; ++k) acc[k] = 0.f;

    const float* hp = head + (size_t)b * D_ * L_ + l;
    for (int d = 0; d < D_; ++d) {
        float hv = hp[(size_t)d * L_];  // coalesced across threads
        const float4* w4 = (const float4*)(&Ws[d][0]);
        float4 w0 = w4[0], w1 = w4[1], w2 = w4[2], w3 = w4[3];
        acc[0]  = fmaf(w0.x, hv, acc[0]);  acc[1]  = fmaf(w0.y, hv, acc[1]);
        acc[2]  = fmaf(w0.z, hv, acc[2]);  acc[3]  = fmaf(w0.w, hv, acc[3]);
        acc[4]  = fmaf(w1.x, hv, acc[4]);  acc[5]  = fmaf(w1.y, hv, acc[5]);
        acc[6]  = fmaf(w1.z, hv, acc[6]);  acc[7]  = fmaf(w1.w, hv, acc[7]);
        acc[8]  = fmaf(w2.x, hv, acc[8]);  acc[9]  = fmaf(w2.y, hv, acc[9]);
        acc[10] = fmaf(w2.z, hv, acc[10]); acc[11] = fmaf(w2.w, hv, acc[11]);
        acc[12] = fmaf(w3.x, hv, acc[12]); acc[13] = fmaf(w3.y, hv, acc[13]);
        acc[14] = fmaf(w3.z, hv, acc[14]); acc[15] = fmaf(w3.w, hv, acc[15]);
    }

    float* op = out + ((size_t)b * D_ + o0) * L_ + l;
#pragma unroll
    for (int oo = 0; oo < 16; ++oo)
        op[(size_t)oo * L_] = acc[oo];
}

// ---------------------------------------------------------------------------
extern "C" void kernel_launch(void* const* d_in, const int* in_sizes, int n_in,
                              void* d_out, int out_size, void* d_ws, size_t ws_size,
                              hipStream_t stream) {
    const float* x  = (const float*)d_in[0];
    const float* Wq = (const float*)d_in[1];
    const float* Wk = (const float*)d_in[2];
    const float* Wv = (const float*)d_in[3];
    const float* Wo = (const float*)d_in[4];
    float* out = (float*)d_out;

    const size_t SEG = (size_t)B_ * NH * DK * L_;   // 1M floats each
    float* Q    = (float*)d_ws;
    float* K    = Q + SEG;
    float* V    = K + SEG;
    float* head = V + SEG;

    proj_kernel<<<dim3(L_ / 256, B_ * NH, 3), 256, 0, stream>>>(x, Wq, Wk, Wv, Q, K, V);
    attn_kernel<<<dim3(L_ / 256, B_ * NH), 256, 0, stream>>>(Q, K, V, head);
    out_kernel<<<dim3(L_ / 256, 8 * B_), 256, 0, stream>>>(head, Wo, out);
}

// Round 4
// 138.899 us; speedup vs baseline: 3.9997x; 1.5714x over previous
//
#include <hip/hip_runtime.h>
#include <hip/hip_bf16.h>

#define B_ 8
#define D_ 128
#define NH 8
#define L_ 1024
#define DK 16

typedef __attribute__((ext_vector_type(4))) short s4;
typedef __attribute__((ext_vector_type(4))) float f4;

static __device__ __forceinline__ unsigned short f2bf(float f) {
    __hip_bfloat16 h = __float2bfloat16(f);
    return *reinterpret_cast<unsigned short*>(&h);
}
static __device__ __forceinline__ unsigned pack2(float a, float b) {
    return (unsigned)f2bf(a) | ((unsigned)f2bf(b) << 16);
}

// 16x16x16 bf16 MFMA: D = A*B + C.  A[m=lane&15][k=(lane>>4)*4+jj],
// B[k=(lane>>4)*4+jj][n=lane&15], C/D[row=(lane>>4)*4+reg][col=lane&15].
#if __has_builtin(__builtin_amdgcn_mfma_f32_16x16x16_bf16)
#define MFMA16(a, b, c) __builtin_amdgcn_mfma_f32_16x16x16_bf16(a, b, c, 0, 0, 0)
#elif __has_builtin(__builtin_amdgcn_mfma_f32_16x16x16bf16_1k)
#define MFMA16(a, b, c) __builtin_amdgcn_mfma_f32_16x16x16bf16_1k(a, b, c, 0, 0, 0)
#else
static __device__ __forceinline__ f4 mfma16_asm(s4 a, s4 b, f4 c) {
    f4 d;
    asm volatile("v_mfma_f32_16x16x16_bf16 %0, %1, %2, %3"
                 : "=&v"(d) : "v"(a), "v"(b), "v"(c));
    return d;
}
#define MFMA16(a, b, c) mfma16_asm(a, b, c)
#endif

// ---------------------------------------------------------------------------
// Kernel A: QKV projection (fp32 math), epilogue emits bf16 in MFMA layouts:
//   Qt[bh][l][k]  (A-operand rows, 32B/row)         which==0
//   Kt[bh][j][k]  (B-operand, 0.25 scale folded)    which==1
//   Vt[bh][v][i]  (A-operand of PV, i-contiguous)   which==2
// grid (L/256, B*Nh, 3), block 256.
// ---------------------------------------------------------------------------
__global__ __launch_bounds__(256)
void proj_kernel(const float* __restrict__ x,
                 const float* __restrict__ Wq,
                 const float* __restrict__ Wk,
                 const float* __restrict__ Wv,
                 unsigned short* __restrict__ Qt,
                 unsigned short* __restrict__ Kt,
                 unsigned short* __restrict__ Vt) {
    const int l  = blockIdx.x * 256 + threadIdx.x;
    const int bh = blockIdx.y;          // bh = b*NH + h
    const int b  = bh >> 3;
    const int h  = bh & 7;
    const int which = blockIdx.z;

    const float* W = (which == 0) ? Wq : (which == 1) ? Wk : Wv;

    // W layout: (Nh, B, Dk, D) -> ((h*B + b)*DK + k)*D_ + d
    __shared__ float Ws[D_][20];        // [d][k], rows 80 B (16B-aligned)
    const float* Wp = W + ((size_t)(h * B_ + b)) * (DK * D_);
    for (int t = threadIdx.x; t < DK * D_; t += 256) {
        int d = t & 127;
        int k = t >> 7;
        Ws[d][k] = Wp[k * D_ + d];      // global coalesced in d
    }
    __syncthreads();

    float acc[DK];
#pragma unroll
    for (int k = 0; k < DK; ++k) acc[k] = 0.f;

    const float* xp = x + (size_t)b * D_ * L_ + l;
    for (int d = 0; d < D_; ++d) {
        float xv = xp[(size_t)d * L_];
        const float4* w4 = (const float4*)(&Ws[d][0]);
        float4 w0 = w4[0], w1 = w4[1], w2 = w4[2], w3 = w4[3];
        acc[0]  = fmaf(w0.x, xv, acc[0]);  acc[1]  = fmaf(w0.y, xv, acc[1]);
        acc[2]  = fmaf(w0.z, xv, acc[2]);  acc[3]  = fmaf(w0.w, xv, acc[3]);
        acc[4]  = fmaf(w1.x, xv, acc[4]);  acc[5]  = fmaf(w1.y, xv, acc[5]);
        acc[6]  = fmaf(w1.z, xv, acc[6]);  acc[7]  = fmaf(w1.w, xv, acc[7]);
        acc[8]  = fmaf(w2.x, xv, acc[8]);  acc[9]  = fmaf(w2.y, xv, acc[9]);
        acc[10] = fmaf(w2.z, xv, acc[10]); acc[11] = fmaf(w2.w, xv, acc[11]);
        acc[12] = fmaf(w3.x, xv, acc[12]); acc[13] = fmaf(w3.y, xv, acc[13]);
        acc[14] = fmaf(w3.z, xv, acc[14]); acc[15] = fmaf(w3.w, xv, acc[15]);
    }

    if (which == 0) {
        unsigned* row = (unsigned*)(Qt + ((size_t)bh * L_ + l) * DK);
        uint4 u0 = {pack2(acc[0], acc[1]),  pack2(acc[2], acc[3]),
                    pack2(acc[4], acc[5]),  pack2(acc[6], acc[7])};
        uint4 u1 = {pack2(acc[8], acc[9]),  pack2(acc[10], acc[11]),
                    pack2(acc[12], acc[13]), pack2(acc[14], acc[15])};
        ((uint4*)row)[0] = u0;
        ((uint4*)row)[1] = u1;
    } else if (which == 1) {
        unsigned* row = (unsigned*)(Kt + ((size_t)bh * L_ + l) * DK);
        uint4 u0 = {pack2(acc[0]*0.25f,  acc[1]*0.25f),
                    pack2(acc[2]*0.25f,  acc[3]*0.25f),
                    pack2(acc[4]*0.25f,  acc[5]*0.25f),
                    pack2(acc[6]*0.25f,  acc[7]*0.25f)};
        uint4 u1 = {pack2(acc[8]*0.25f,  acc[9]*0.25f),
                    pack2(acc[10]*0.25f, acc[11]*0.25f),
                    pack2(acc[12]*0.25f, acc[13]*0.25f),
                    pack2(acc[14]*0.25f, acc[15]*0.25f)};
        ((uint4*)row)[0] = u0;
        ((uint4*)row)[1] = u1;
    } else {
        __hip_bfloat16* vp = (__hip_bfloat16*)Vt;
#pragma unroll
        for (int v = 0; v < DK; ++v)
            vp[((size_t)bh * DK + v) * L_ + l] = __float2bfloat16(acc[v]);
    }
}

// ---------------------------------------------------------------------------
// Kernel B: MFMA attention.  One wave per (bh, 16-wide j-tile); zero LDS.
// Per 16-i step:  S = Qt_frag * Kt_frag (16x16x16), P = exp(S) (C-layout ==
// B-layout for the square shape!), O += Vt_frag * P.  lsum = running sum of
// P per column, reduced across quads with shfl_xor at the end.
// grid (16, 64), block 256 (4 waves -> 4 j-tiles).
// ---------------------------------------------------------------------------
__global__ __launch_bounds__(256)
void attn_mfma_kernel(const unsigned short* __restrict__ Qt,
                      const unsigned short* __restrict__ Kt,
                      const unsigned short* __restrict__ Vt,
                      float* __restrict__ head) {
    const int lane = threadIdx.x & 63;
    const int wv   = threadIdx.x >> 6;
    const int m    = lane & 15;          // tile row/col index
    const int q    = lane >> 4;          // quad
    const int jt   = blockIdx.x * 4 + wv;
    const int j0   = jt * 16;
    const int bh   = blockIdx.y;

    // B-fragment of K (loop-invariant): B[k=q*4+jj][n=m] = Kt[bh][j0+m][q*4+jj]
    s4 bk = *(const s4*)(Kt + ((size_t)bh * L_ + j0 + m) * DK + q * 4);

    f4 O = {0.f, 0.f, 0.f, 0.f};
    float ls = 0.f;
    const unsigned short* qbase = Qt + (size_t)bh * L_ * DK + q * 4;
    const unsigned short* vbase = Vt + ((size_t)bh * DK + m) * L_ + q * 4;

    for (int i0 = 0; i0 < L_; i0 += 16) {
        // A[m][k=q*4+jj] = Qt[bh][i0+m][q*4+jj]
        s4 aq = *(const s4*)(qbase + (size_t)(i0 + m) * DK);
        // A2[m=v][k=jj] = Vt[bh][m][i0+q*4+jj]
        s4 av = *(const s4*)(vbase + i0);

        f4 z = {0.f, 0.f, 0.f, 0.f};
        f4 S = MFMA16(aq, bk, z);        // S[i0+q*4+r][j0+m]

        float p0 = __expf(S[0]), p1 = __expf(S[1]);
        float p2 = __expf(S[2]), p3 = __expf(S[3]);
        ls += (p0 + p1) + (p2 + p3);

        s4 pb;
        pb[0] = (short)f2bf(p0); pb[1] = (short)f2bf(p1);
        pb[2] = (short)f2bf(p2); pb[3] = (short)f2bf(p3);

        O = MFMA16(av, pb, O);           // O[v=q*4+r][j0+m] += V*P
    }

    // full column sum over i: combine the 4 quads holding column j0+m
    ls += __shfl_xor(ls, 16, 64);
    ls += __shfl_xor(ls, 32, 64);
    const float inv = 1.f / ls;

    float* hp = head + ((size_t)bh * DK + q * 4) * L_ + j0 + m;
    hp[0 * L_] = O[0] * inv;
    hp[1 * L_] = O[1] * inv;
    hp[2 * L_] = O[2] * inv;
    hp[3 * L_] = O[3] * inv;
}

// ---------------------------------------------------------------------------
// Kernel C: out[b,o,l] = sum_d Wo[b,o,d] * head[b,d,l]   (unchanged)
// grid (L/256, 8*B), block 256.
// ---------------------------------------------------------------------------
__global__ __launch_bounds__(256)
void out_kernel(const float* __restrict__ head,
                const float* __restrict__ Wo,
                float* __restrict__ out) {
    const int l  = blockIdx.x * 256 + threadIdx.x;
    const int oc = blockIdx.y & 7;
    const int b  = blockIdx.y >> 3;
    const int o0 = oc * 16;

    __shared__ float Ws[D_][20];
    const float* Wb = Wo + (size_t)b * D_ * D_;
    for (int t = threadIdx.x; t < 16 * D_; t += 256) {
        int d  = t & 127;
        int oo = t >> 7;
        Ws[d][oo] = Wb[(size_t)(o0 + oo) * D_ + d];
    }
    __syncthreads();

    float acc[16];
#pragma unroll
    for (int k = 0; k < 16; ++k) acc[k] = 0.f;

    const float* hp = head + (size_t)b * D_ * L_ + l;
    for (int d = 0; d < D_; ++d) {
        float hv = hp[(size_t)d * L_];
        const float4* w4 = (const float4*)(&Ws[d][0]);
        float4 w0 = w4[0], w1 = w4[1], w2 = w4[2], w3 = w4[3];
        acc[0]  = fmaf(w0.x, hv, acc[0]);  acc[1]  = fmaf(w0.y, hv, acc[1]);
        acc[2]  = fmaf(w0.z, hv, acc[2]);  acc[3]  = fmaf(w0.w, hv, acc[3]);
        acc[4]  = fmaf(w1.x, hv, acc[4]);  acc[5]  = fmaf(w1.y, hv, acc[5]);
        acc[6]  = fmaf(w1.z, hv, acc[6]);  acc[7]  = fmaf(w1.w, hv, acc[7]);
        acc[8]  = fmaf(w2.x, hv, acc[8]);  acc[9]  = fmaf(w2.y, hv, acc[9]);
        acc[10] = fmaf(w2.z, hv, acc[10]); acc[11] = fmaf(w2.w, hv, acc[11]);
        acc[12] = fmaf(w3.x, hv, acc[12]); acc[13] = fmaf(w3.y, hv, acc[13]);
        acc[14] = fmaf(w3.z, hv, acc[14]); acc[15] = fmaf(w3.w, hv, acc[15]);
    }

    float* op = out + ((size_t)b * D_ + o0) * L_ + l;
#pragma unroll
    for (int oo = 0; oo < 16; ++oo)
        op[(size_t)oo * L_] = acc[oo];
}

// ---------------------------------------------------------------------------
extern "C" void kernel_launch(void* const* d_in, const int* in_sizes, int n_in,
                              void* d_out, int out_size, void* d_ws, size_t ws_size,
                              hipStream_t stream) {
    const float* x  = (const float*)d_in[0];
    const float* Wq = (const float*)d_in[1];
    const float* Wk = (const float*)d_in[2];
    const float* Wv = (const float*)d_in[3];
    const float* Wo = (const float*)d_in[4];
    float* out = (float*)d_out;

    const size_t SEG = (size_t)B_ * NH * DK * L_;   // 1,048,576 elements
    unsigned short* Qt = (unsigned short*)d_ws;     // bf16, 2 MB
    unsigned short* Kt = Qt + SEG;                  // bf16, 2 MB
    unsigned short* Vt = Kt + SEG;                  // bf16, 2 MB
    float* head = (float*)(Vt + SEG);               // fp32, 4 MB

    proj_kernel<<<dim3(L_ / 256, B_ * NH, 3), 256, 0, stream>>>(x, Wq, Wk, Wv, Qt, Kt, Vt);
    attn_mfma_kernel<<<dim3(16, B_ * NH), 256, 0, stream>>>(Qt, Kt, Vt, head);
    out_kernel<<<dim3(L_ / 256, 8 * B_), 256, 0, stream>>>(head, Wo, out);
}

// Round 5
// 129.823 us; speedup vs baseline: 4.2794x; 1.0699x over previous
//
#include <hip/hip_runtime.h>
#include <hip/hip_bf16.h>

#define B_ 8
#define D_ 128
#define NH 8
#define L_ 1024
#define DK 16

typedef __attribute__((ext_vector_type(4))) short s4;
typedef __attribute__((ext_vector_type(4))) float f4;

static __device__ __forceinline__ unsigned short f2bf(float f) {
    __hip_bfloat16 h = __float2bfloat16(f);
    return *reinterpret_cast<unsigned short*>(&h);
}
static __device__ __forceinline__ unsigned pack2(float a, float b) {
    return (unsigned)f2bf(a) | ((unsigned)f2bf(b) << 16);
}
static __device__ __forceinline__ s4 pack4(float a, float b, float c, float d) {
    union { unsigned u[2]; s4 v; } un;
    un.u[0] = pack2(a, b);
    un.u[1] = pack2(c, d);
    return un.v;
}

// 16x16x16 bf16 MFMA: D = A*B + C.  A[m=lane&15][k=(lane>>4)*4+jj],
// B[k=(lane>>4)*4+jj][n=lane&15], C/D[row=(lane>>4)*4+reg][col=lane&15].
#if __has_builtin(__builtin_amdgcn_mfma_f32_16x16x16_bf16)
#define MFMA16(a, b, c) __builtin_amdgcn_mfma_f32_16x16x16_bf16(a, b, c, 0, 0, 0)
#elif __has_builtin(__builtin_amdgcn_mfma_f32_16x16x16bf16_1k)
#define MFMA16(a, b, c) __builtin_amdgcn_mfma_f32_16x16x16bf16_1k(a, b, c, 0, 0, 0)
#else
static __device__ __forceinline__ f4 mfma16_asm(s4 a, s4 b, f4 c) {
    f4 d;
    asm volatile("v_mfma_f32_16x16x16_bf16 %0, %1, %2, %3"
                 : "=&v"(d) : "v"(a), "v"(b), "v"(c));
    return d;
}
#define MFMA16(a, b, c) mfma16_asm(a, b, c)
#endif

// ---------------------------------------------------------------------------
// Kernel 0: transpose-convert x[b][d][l] fp32 -> xT[b][l][d] bf16.
// grid (L/64, B), block 256.  LDS tile 64l x 128d (+2 pad shorts/row).
// ---------------------------------------------------------------------------
__global__ __launch_bounds__(256)
void xt_kernel(const float* __restrict__ x, unsigned short* __restrict__ xT) {
    const int b  = blockIdx.y;
    const int l0 = blockIdx.x * 64;
    __shared__ unsigned short tile[64][130];   // rows 260 B (4B-aligned)

#pragma unroll
    for (int it = 0; it < 32; ++it) {
        int idx = it * 256 + threadIdx.x;
        int d  = idx >> 6;
        int ll = idx & 63;
        tile[ll][d] = f2bf(x[((size_t)b * D_ + d) * L_ + l0 + ll]);  // coalesced
    }
    __syncthreads();

    unsigned* dst = (unsigned*)(xT + (size_t)b * L_ * D_);
#pragma unroll
    for (int it = 0; it < 16; ++it) {
        int idx = it * 256 + threadIdx.x;
        int ll = idx >> 6;
        int u  = idx & 63;
        const unsigned* row = (const unsigned*)&tile[ll][0];
        dst[(size_t)(l0 + ll) * 64 + u] = row[u];   // row-contiguous write
    }
}

// ---------------------------------------------------------------------------
// Kernel 1: MFMA QKV projection.  One wave per (bh, which, 32-wide l-tile).
// A = W row-major (float4 + cvt), B = xT rows (b64).  K = 128 -> 8 steps,
// 2 MFMA/step (two 16-col halves).  Epilogue writes MFMA-ready layouts:
//   Qt[bh][l][k]  (packed b64)       which==0
//   Kt[bh][j][k]  *0.25, packed b64  which==1
//   Vt[bh][v][i]  (4+4 short stores) which==2
// grid (8, 64, 3), block 256.
// ---------------------------------------------------------------------------
__global__ __launch_bounds__(256)
void proj_kernel(const unsigned short* __restrict__ xT,
                 const float* __restrict__ Wq,
                 const float* __restrict__ Wk,
                 const float* __restrict__ Wv,
                 unsigned short* __restrict__ Qt,
                 unsigned short* __restrict__ Kt,
                 unsigned short* __restrict__ Vt) {
    const int lane = threadIdx.x & 63;
    const int wv   = threadIdx.x >> 6;
    const int m = lane & 15, q = lane >> 4;
    const int bh = blockIdx.y, b = bh >> 3, h = bh & 7;
    const int which = blockIdx.z;
    const int n0 = (blockIdx.x * 4 + wv) * 32;

    const float* W = (which == 0) ? Wq : (which == 1) ? Wk : Wv;
    const float* Wrow = W + ((size_t)((h * B_ + b) * DK + m)) * D_;  // A row m
    const unsigned short* x0 = xT + ((size_t)b * L_ + n0 + m) * D_;
    const unsigned short* x1 = x0 + 16 * D_;

    f4 acc0 = {0.f, 0.f, 0.f, 0.f}, acc1 = {0.f, 0.f, 0.f, 0.f};
#pragma unroll
    for (int kb = 0; kb < 8; ++kb) {
        const int k4 = kb * 16 + q * 4;
        float4 wf = *(const float4*)(Wrow + k4);
        s4 a  = pack4(wf.x, wf.y, wf.z, wf.w);
        s4 b0 = *(const s4*)(x0 + k4);
        s4 b1 = *(const s4*)(x1 + k4);
        acc0 = MFMA16(a, b0, acc0);
        acc1 = MFMA16(a, b1, acc1);
    }

    if (which == 2) {
        // D[row=v=q*4+r][col=i=n0(+16)+m] -> Vt[bh][v][i]
        unsigned short* vp = Vt + ((size_t)bh * DK + q * 4) * L_ + n0 + m;
        vp[0]      = f2bf(acc0[0]); vp[L_]     = f2bf(acc0[1]);
        vp[2 * L_] = f2bf(acc0[2]); vp[3 * L_] = f2bf(acc0[3]);
        vp += 16;
        vp[0]      = f2bf(acc1[0]); vp[L_]     = f2bf(acc1[1]);
        vp[2 * L_] = f2bf(acc1[2]); vp[3 * L_] = f2bf(acc1[3]);
    } else {
        const float sc = (which == 1) ? 0.25f : 1.0f;
        unsigned short* T = (which == 0) ? Qt : Kt;
        uint2 u0, u1;
        u0.x = pack2(acc0[0] * sc, acc0[1] * sc);
        u0.y = pack2(acc0[2] * sc, acc0[3] * sc);
        u1.x = pack2(acc1[0] * sc, acc1[1] * sc);
        u1.y = pack2(acc1[2] * sc, acc1[3] * sc);
        // D[row=k=q*4+r][col=l] -> T[bh][l][k]: 4 consecutive k per lane
        *(uint2*)(T + ((size_t)bh * L_ + n0 + m) * DK + q * 4)      = u0;
        *(uint2*)(T + ((size_t)bh * L_ + n0 + 16 + m) * DK + q * 4) = u1;
    }
}

// ---------------------------------------------------------------------------
// Kernel 2: MFMA attention (zero LDS).  One wave per (bh, 16-wide j-tile).
// S = Qt*Kt, P = exp(S) (C-layout == B-layout), O += Vt*P, lsum via shfl.
// Writes headT[b][l][d] bf16 (packed b64).  grid (16, 64), block 256.
// ---------------------------------------------------------------------------
__global__ __launch_bounds__(256)
void attn_mfma_kernel(const unsigned short* __restrict__ Qt,
                      const unsigned short* __restrict__ Kt,
                      const unsigned short* __restrict__ Vt,
                      unsigned short* __restrict__ headT) {
    const int lane = threadIdx.x & 63;
    const int wv   = threadIdx.x >> 6;
    const int m    = lane & 15;
    const int q    = lane >> 4;
    const int jt   = blockIdx.x * 4 + wv;
    const int j0   = jt * 16;
    const int bh   = blockIdx.y, b = bh >> 3, h = bh & 7;

    s4 bk = *(const s4*)(Kt + ((size_t)bh * L_ + j0 + m) * DK + q * 4);

    f4 O = {0.f, 0.f, 0.f, 0.f};
    float ls = 0.f;
    const unsigned short* qbase = Qt + (size_t)bh * L_ * DK + q * 4;
    const unsigned short* vbase = Vt + ((size_t)bh * DK + m) * L_ + q * 4;

    for (int i0 = 0; i0 < L_; i0 += 16) {
        s4 aq = *(const s4*)(qbase + (size_t)(i0 + m) * DK);
        s4 av = *(const s4*)(vbase + i0);

        f4 z = {0.f, 0.f, 0.f, 0.f};
        f4 S = MFMA16(aq, bk, z);        // S[i0+q*4+r][j0+m]

        float p0 = __expf(S[0]), p1 = __expf(S[1]);
        float p2 = __expf(S[2]), p3 = __expf(S[3]);
        ls += (p0 + p1) + (p2 + p3);

        s4 pb;
        pb[0] = (short)f2bf(p0); pb[1] = (short)f2bf(p1);
        pb[2] = (short)f2bf(p2); pb[3] = (short)f2bf(p3);

        O = MFMA16(av, pb, O);           // O[v=q*4+r][j0+m] += V*P
    }

    ls += __shfl_xor(ls, 16, 64);
    ls += __shfl_xor(ls, 32, 64);
    const float inv = 1.f / ls;

    // O rows are 4 consecutive d = h*16 + q*4 + r at column l = j0+m
    uint2 o;
    o.x = pack2(O[0] * inv, O[1] * inv);
    o.y = pack2(O[2] * inv, O[3] * inv);
    *(uint2*)(headT + ((size_t)b * L_ + j0 + m) * D_ + h * DK + q * 4) = o;
}

// ---------------------------------------------------------------------------
// Kernel 3: MFMA output projection.  out[b][o][l] = Wo[b](128x128) @ head.
// One wave per (b, 16-row o-chunk, 32-wide l-tile).  grid (64, 8), block 256.
// ---------------------------------------------------------------------------
__global__ __launch_bounds__(256)
void out_kernel(const unsigned short* __restrict__ headT,
                const float* __restrict__ Wo,
                float* __restrict__ out) {
    const int lane = threadIdx.x & 63;
    const int wv   = threadIdx.x >> 6;
    const int m = lane & 15, q = lane >> 4;
    const int task = blockIdx.x * 4 + wv;   // 0..255
    const int oc = task >> 5;               // 0..7
    const int n0 = (task & 31) * 32;
    const int b  = blockIdx.y;
    const int o0 = oc * 16;

    const float* Wrow = Wo + ((size_t)b * D_ + o0 + m) * D_;
    const unsigned short* h0 = headT + ((size_t)b * L_ + n0 + m) * D_;
    const unsigned short* h1 = h0 + 16 * D_;

    f4 acc0 = {0.f, 0.f, 0.f, 0.f}, acc1 = {0.f, 0.f, 0.f, 0.f};
#pragma unroll
    for (int kb = 0; kb < 8; ++kb) {
        const int k4 = kb * 16 + q * 4;
        float4 wf = *(const float4*)(Wrow + k4);
        s4 a  = pack4(wf.x, wf.y, wf.z, wf.w);
        s4 b0 = *(const s4*)(h0 + k4);
        s4 b1 = *(const s4*)(h1 + k4);
        acc0 = MFMA16(a, b0, acc0);
        acc1 = MFMA16(a, b1, acc1);
    }

    // D[row=o=o0+q*4+r][col=l=n0(+16)+m] -> out fp32
    float* op = out + ((size_t)b * D_ + o0 + q * 4) * L_ + n0 + m;
    op[0]      = acc0[0]; op[L_]     = acc0[1];
    op[2 * L_] = acc0[2]; op[3 * L_] = acc0[3];
    op += 16;
    op[0]      = acc1[0]; op[L_]     = acc1[1];
    op[2 * L_] = acc1[2]; op[3 * L_] = acc1[3];
}

// ---------------------------------------------------------------------------
extern "C" void kernel_launch(void* const* d_in, const int* in_sizes, int n_in,
                              void* d_out, int out_size, void* d_ws, size_t ws_size,
                              hipStream_t stream) {
    const float* x  = (const float*)d_in[0];
    const float* Wq = (const float*)d_in[1];
    const float* Wk = (const float*)d_in[2];
    const float* Wv = (const float*)d_in[3];
    const float* Wo = (const float*)d_in[4];
    float* out = (float*)d_out;

    const size_t SEG = (size_t)B_ * NH * DK * L_;   // 1,048,576 elements
    unsigned short* xT    = (unsigned short*)d_ws;  // bf16 [b][l][d],  2 MB
    unsigned short* Qt    = xT + SEG;               // bf16 [bh][l][k], 2 MB
    unsigned short* Kt    = Qt + SEG;               // bf16 [bh][j][k], 2 MB
    unsigned short* Vt    = Kt + SEG;               // bf16 [bh][v][i], 2 MB
    unsigned short* headT = Vt + SEG;               // bf16 [b][l][d],  2 MB

    xt_kernel  <<<dim3(L_ / 64, B_),    256, 0, stream>>>(x, xT);
    proj_kernel<<<dim3(8, B_ * NH, 3),  256, 0, stream>>>(xT, Wq, Wk, Wv, Qt, Kt, Vt);
    attn_mfma_kernel<<<dim3(16, B_ * NH), 256, 0, stream>>>(Qt, Kt, Vt, headT);
    out_kernel <<<dim3(64, B_),         256, 0, stream>>>(headT, Wo, out);
}

// Round 6
// 119.584 us; speedup vs baseline: 4.6457x; 1.0856x over previous
//
#include <hip/hip_runtime.h>
#include <hip/hip_bf16.h>

#define B_ 8
#define D_ 128
#define NH 8
#define L_ 1024
#define DK 16

typedef __attribute__((ext_vector_type(4))) short s4;
typedef __attribute__((ext_vector_type(4))) float f4;

static __device__ __forceinline__ unsigned short f2bf(float f) {
    __hip_bfloat16 h = __float2bfloat16(f);
    return *reinterpret_cast<unsigned short*>(&h);
}
static __device__ __forceinline__ unsigned pack2(float a, float b) {
    return (unsigned)f2bf(a) | ((unsigned)f2bf(b) << 16);
}
static __device__ __forceinline__ s4 pack4(float a, float b, float c, float d) {
    union { unsigned u[2]; s4 v; } un;
    un.u[0] = pack2(a, b);
    un.u[1] = pack2(c, d);
    return un.v;
}

// 16x16x16 bf16 MFMA: D = A*B + C.  A[m=lane&15][k=(lane>>4)*4+jj],
// B[k=(lane>>4)*4+jj][n=lane&15], C/D[row=(lane>>4)*4+reg][col=lane&15].
// (A/B/C mapping HW-verified in rounds 4-5 end-to-end.)
#if __has_builtin(__builtin_amdgcn_mfma_f32_16x16x16_bf16)
#define MFMA16(a, b, c) __builtin_amdgcn_mfma_f32_16x16x16_bf16(a, b, c, 0, 0, 0)
#elif __has_builtin(__builtin_amdgcn_mfma_f32_16x16x16bf16_1k)
#define MFMA16(a, b, c) __builtin_amdgcn_mfma_f32_16x16x16bf16_1k(a, b, c, 0, 0, 0)
#else
static __device__ __forceinline__ f4 mfma16_asm(s4 a, s4 b, f4 c) {
    f4 d;
    asm volatile("v_mfma_f32_16x16x16_bf16 %0, %1, %2, %3"
                 : "=&v"(d) : "v"(a), "v"(b), "v"(c));
    return d;
}
#define MFMA16(a, b, c) mfma16_asm(a, b, c)
#endif

// ---------------------------------------------------------------------------
// Kernel 1: MFMA QKV projection, x read transposed directly from global
// (fp32 dword loads, coalesced along l within each quad-row; bf16 pack on
// the fly — same rounding as the old xt round-trip).  One wave per
// (bh, which, 32-wide l-tile).  K = 128 -> 8 steps, 2 MFMA/step.
// Epilogue writes MFMA-ready layouts:
//   Qt[bh][l][k]  (packed b64)       which==0
//   Kt[bh][j][k]  *0.25, packed b64  which==1
//   Vt[bh][v][i]  (short stores)     which==2
// grid (8, 64, 3), block 256.
// ---------------------------------------------------------------------------
__global__ __launch_bounds__(256)
void proj_kernel(const float* __restrict__ x,
                 const float* __restrict__ Wq,
                 const float* __restrict__ Wk,
                 const float* __restrict__ Wv,
                 unsigned short* __restrict__ Qt,
                 unsigned short* __restrict__ Kt,
                 unsigned short* __restrict__ Vt) {
    const int lane = threadIdx.x & 63;
    const int wv   = threadIdx.x >> 6;
    const int m = lane & 15, q = lane >> 4;
    const int bh = blockIdx.y, b = bh >> 3, h = bh & 7;
    const int which = blockIdx.z;
    const int n0 = (blockIdx.x * 4 + wv) * 32;

    const float* W = (which == 0) ? Wq : (which == 1) ? Wk : Wv;
    const float* Wrow = W + ((size_t)((h * B_ + b) * DK + m)) * D_;  // A row m
    // B-operand: xbf[b][k][n0(+16)+m]
    const float* xb = x + (size_t)b * D_ * L_ + n0 + m;

    f4 acc0 = {0.f, 0.f, 0.f, 0.f}, acc1 = {0.f, 0.f, 0.f, 0.f};
#pragma unroll
    for (int kb = 0; kb < 8; ++kb) {
        const int k4 = kb * 16 + q * 4;
        float4 wf = *(const float4*)(Wrow + k4);
        s4 a = pack4(wf.x, wf.y, wf.z, wf.w);

        const float* xc = xb + (size_t)k4 * L_;
        float b00 = xc[0];          float b01 = xc[L_];
        float b02 = xc[2 * L_];     float b03 = xc[3 * L_];
        float b10 = xc[16];         float b11 = xc[L_ + 16];
        float b12 = xc[2 * L_ + 16];float b13 = xc[3 * L_ + 16];
        s4 bf0 = pack4(b00, b01, b02, b03);
        s4 bf1 = pack4(b10, b11, b12, b13);

        acc0 = MFMA16(a, bf0, acc0);
        acc1 = MFMA16(a, bf1, acc1);
    }

    if (which == 2) {
        // D[row=v=q*4+r][col=i=n0(+16)+m] -> Vt[bh][v][i]
        unsigned short* vp = Vt + ((size_t)bh * DK + q * 4) * L_ + n0 + m;
        vp[0]      = f2bf(acc0[0]); vp[L_]     = f2bf(acc0[1]);
        vp[2 * L_] = f2bf(acc0[2]); vp[3 * L_] = f2bf(acc0[3]);
        vp += 16;
        vp[0]      = f2bf(acc1[0]); vp[L_]     = f2bf(acc1[1]);
        vp[2 * L_] = f2bf(acc1[2]); vp[3 * L_] = f2bf(acc1[3]);
    } else {
        const float sc = (which == 1) ? 0.25f : 1.0f;
        unsigned short* T = (which == 0) ? Qt : Kt;
        uint2 u0, u1;
        u0.x = pack2(acc0[0] * sc, acc0[1] * sc);
        u0.y = pack2(acc0[2] * sc, acc0[3] * sc);
        u1.x = pack2(acc1[0] * sc, acc1[1] * sc);
        u1.y = pack2(acc1[2] * sc, acc1[3] * sc);
        // D[row=k=q*4+r][col=l] -> T[bh][l][k]: 4 consecutive k per lane
        *(uint2*)(T + ((size_t)bh * L_ + n0 + m) * DK + q * 4)      = u0;
        *(uint2*)(T + ((size_t)bh * L_ + n0 + 16 + m) * DK + q * 4) = u1;
    }
}

// ---------------------------------------------------------------------------
// Kernel 2: MFMA attention (zero LDS).  One wave per (bh, 16-wide j-tile).
// S = Qt*Kt, P = exp(S) (C-layout == B-layout), O += Vt*P, lsum via shfl.
// Writes headT[b][l][d] bf16 (packed b64).  grid (16, 64), block 256.
// ---------------------------------------------------------------------------
__global__ __launch_bounds__(256)
void attn_mfma_kernel(const unsigned short* __restrict__ Qt,
                      const unsigned short* __restrict__ Kt,
                      const unsigned short* __restrict__ Vt,
                      unsigned short* __restrict__ headT) {
    const int lane = threadIdx.x & 63;
    const int wv   = threadIdx.x >> 6;
    const int m    = lane & 15;
    const int q    = lane >> 4;
    const int jt   = blockIdx.x * 4 + wv;
    const int j0   = jt * 16;
    const int bh   = blockIdx.y, b = bh >> 3, h = bh & 7;

    s4 bk = *(const s4*)(Kt + ((size_t)bh * L_ + j0 + m) * DK + q * 4);

    f4 O = {0.f, 0.f, 0.f, 0.f};
    float ls = 0.f;
    const unsigned short* qbase = Qt + (size_t)bh * L_ * DK + q * 4;
    const unsigned short* vbase = Vt + ((size_t)bh * DK + m) * L_ + q * 4;

#pragma unroll 4
    for (int i0 = 0; i0 < L_; i0 += 16) {
        s4 aq = *(const s4*)(qbase + (size_t)(i0 + m) * DK);
        s4 av = *(const s4*)(vbase + i0);

        f4 z = {0.f, 0.f, 0.f, 0.f};
        f4 S = MFMA16(aq, bk, z);        // S[i0+q*4+r][j0+m]

        float p0 = __expf(S[0]), p1 = __expf(S[1]);
        float p2 = __expf(S[2]), p3 = __expf(S[3]);
        ls += (p0 + p1) + (p2 + p3);

        s4 pb;
        pb[0] = (short)f2bf(p0); pb[1] = (short)f2bf(p1);
        pb[2] = (short)f2bf(p2); pb[3] = (short)f2bf(p3);

        O = MFMA16(av, pb, O);           // O[v=q*4+r][j0+m] += V*P
    }

    ls += __shfl_xor(ls, 16, 64);
    ls += __shfl_xor(ls, 32, 64);
    const float inv = 1.f / ls;

    // O rows are 4 consecutive d = h*16 + q*4 + r at column l = j0+m
    uint2 o;
    o.x = pack2(O[0] * inv, O[1] * inv);
    o.y = pack2(O[2] * inv, O[3] * inv);
    *(uint2*)(headT + ((size_t)b * L_ + j0 + m) * D_ + h * DK + q * 4) = o;
}

// ---------------------------------------------------------------------------
// Kernel 3: MFMA output projection.  out[b][o][l] = Wo[b](128x128) @ head.
// One wave per (b, 16-row o-chunk, 32-wide l-tile).  grid (64, 8), block 256.
// ---------------------------------------------------------------------------
__global__ __launch_bounds__(256)
void out_kernel(const unsigned short* __restrict__ headT,
                const float* __restrict__ Wo,
                float* __restrict__ out) {
    const int lane = threadIdx.x & 63;
    const int wv   = threadIdx.x >> 6;
    const int m = lane & 15, q = lane >> 4;
    const int task = blockIdx.x * 4 + wv;   // 0..255
    const int oc = task >> 5;               // 0..7
    const int n0 = (task & 31) * 32;
    const int b  = blockIdx.y;
    const int o0 = oc * 16;

    const float* Wrow = Wo + ((size_t)b * D_ + o0 + m) * D_;
    const unsigned short* h0 = headT + ((size_t)b * L_ + n0 + m) * D_;
    const unsigned short* h1 = h0 + 16 * D_;

    f4 acc0 = {0.f, 0.f, 0.f, 0.f}, acc1 = {0.f, 0.f, 0.f, 0.f};
#pragma unroll
    for (int kb = 0; kb < 8; ++kb) {
        const int k4 = kb * 16 + q * 4;
        float4 wf = *(const float4*)(Wrow + k4);
        s4 a  = pack4(wf.x, wf.y, wf.z, wf.w);
        s4 b0 = *(const s4*)(h0 + k4);
        s4 b1 = *(const s4*)(h1 + k4);
        acc0 = MFMA16(a, b0, acc0);
        acc1 = MFMA16(a, b1, acc1);
    }

    // D[row=o=o0+q*4+r][col=l=n0(+16)+m] -> out fp32
    float* op = out + ((size_t)b * D_ + o0 + q * 4) * L_ + n0 + m;
    op[0]      = acc0[0]; op[L_]     = acc0[1];
    op[2 * L_] = acc0[2]; op[3 * L_] = acc0[3];
    op += 16;
    op[0]      = acc1[0]; op[L_]     = acc1[1];
    op[2 * L_] = acc1[2]; op[3 * L_] = acc1[3];
}

// ---------------------------------------------------------------------------
extern "C" void kernel_launch(void* const* d_in, const int* in_sizes, int n_in,
                              void* d_out, int out_size, void* d_ws, size_t ws_size,
                              hipStream_t stream) {
    const float* x  = (const float*)d_in[0];
    const float* Wq = (const float*)d_in[1];
    const float* Wk = (const float*)d_in[2];
    const float* Wv = (const float*)d_in[3];
    const float* Wo = (const float*)d_in[4];
    float* out = (float*)d_out;

    const size_t SEG = (size_t)B_ * NH * DK * L_;   // 1,048,576 elements
    unsigned short* Qt    = (unsigned short*)d_ws;  // bf16 [bh][l][k], 2 MB
    unsigned short* Kt    = Qt + SEG;               // bf16 [bh][j][k], 2 MB
    unsigned short* Vt    = Kt + SEG;               // bf16 [bh][v][i], 2 MB
    unsigned short* headT = Vt + SEG;               // bf16 [b][l][d],  2 MB

    proj_kernel<<<dim3(8, B_ * NH, 3),  256, 0, stream>>>(x, Wq, Wk, Wv, Qt, Kt, Vt);
    attn_mfma_kernel<<<dim3(16, B_ * NH), 256, 0, stream>>>(Qt, Kt, Vt, headT);
    out_kernel <<<dim3(64, B_),         256, 0, stream>>>(headT, Wo, out);
}

// Round 7
// 103.577 us; speedup vs baseline: 5.3637x; 1.1545x over previous
//
#include <hip/hip_runtime.h>
#include <hip/hip_bf16.h>

#define B_ 8
#define D_ 128
#define NH 8
#define L_ 1024
#define DK 16

typedef __attribute__((ext_vector_type(4))) short s4;
typedef __attribute__((ext_vector_type(4))) float f4;

static __device__ __forceinline__ unsigned short f2bf(float f) {
    __hip_bfloat16 h = __float2bfloat16(f);
    return *reinterpret_cast<unsigned short*>(&h);
}
static __device__ __forceinline__ unsigned pack2(float a, float b) {
    return (unsigned)f2bf(a) | ((unsigned)f2bf(b) << 16);
}
static __device__ __forceinline__ s4 pack4(float a, float b, float c, float d) {
    union { unsigned u[2]; s4 v; } un;
    un.u[0] = pack2(a, b);
    un.u[1] = pack2(c, d);
    return un.v;
}

// 16x16x16 bf16 MFMA: D = A*B + C.  A[m=lane&15][k=(lane>>4)*4+jj],
// B[k=(lane>>4)*4+jj][n=lane&15], C/D[row=(lane>>4)*4+reg][col=lane&15].
// (A/B/C mapping HW-verified in rounds 4-6 end-to-end.)
#if __has_builtin(__builtin_amdgcn_mfma_f32_16x16x16_bf16)
#define MFMA16(a, b, c) __builtin_amdgcn_mfma_f32_16x16x16_bf16(a, b, c, 0, 0, 0)
#elif __has_builtin(__builtin_amdgcn_mfma_f32_16x16x16bf16_1k)
#define MFMA16(a, b, c) __builtin_amdgcn_mfma_f32_16x16x16bf16_1k(a, b, c, 0, 0, 0)
#else
static __device__ __forceinline__ f4 mfma16_asm(s4 a, s4 b, f4 c) {
    f4 d;
    asm volatile("v_mfma_f32_16x16x16_bf16 %0, %1, %2, %3"
                 : "=&v"(d) : "v"(a), "v"(b), "v"(c));
    return d;
}
#define MFMA16(a, b, c) mfma16_asm(a, b, c)
#endif

// ---------------------------------------------------------------------------
// Kernel 1: MFMA QKV projection, x read transposed directly from global
// (fp32 dword loads; bf16 pack on the fly).  One wave per (bh, which,
// 32-wide l-tile).  K = 128 -> 8 steps, 2 MFMA/step.  Epilogue:
//   Qt[bh][l][k]  (packed b64)       which==0
//   Kt[bh][j][k]  *0.25, packed b64  which==1
//   Vt[bh][v][i]  (short stores)     which==2
// grid (8, 64, 3), block 256.   (unchanged from R6)
// ---------------------------------------------------------------------------
__global__ __launch_bounds__(256)
void proj_kernel(const float* __restrict__ x,
                 const float* __restrict__ Wq,
                 const float* __restrict__ Wk,
                 const float* __restrict__ Wv,
                 unsigned short* __restrict__ Qt,
                 unsigned short* __restrict__ Kt,
                 unsigned short* __restrict__ Vt) {
    const int lane = threadIdx.x & 63;
    const int wv   = threadIdx.x >> 6;
    const int m = lane & 15, q = lane >> 4;
    const int bh = blockIdx.y, b = bh >> 3, h = bh & 7;
    const int which = blockIdx.z;
    const int n0 = (blockIdx.x * 4 + wv) * 32;

    const float* W = (which == 0) ? Wq : (which == 1) ? Wk : Wv;
    const float* Wrow = W + ((size_t)((h * B_ + b) * DK + m)) * D_;  // A row m
    const float* xb = x + (size_t)b * D_ * L_ + n0 + m;

    f4 acc0 = {0.f, 0.f, 0.f, 0.f}, acc1 = {0.f, 0.f, 0.f, 0.f};
#pragma unroll
    for (int kb = 0; kb < 8; ++kb) {
        const int k4 = kb * 16 + q * 4;
        float4 wf = *(const float4*)(Wrow + k4);
        s4 a = pack4(wf.x, wf.y, wf.z, wf.w);

        const float* xc = xb + (size_t)k4 * L_;
        float b00 = xc[0];          float b01 = xc[L_];
        float b02 = xc[2 * L_];     float b03 = xc[3 * L_];
        float b10 = xc[16];         float b11 = xc[L_ + 16];
        float b12 = xc[2 * L_ + 16];float b13 = xc[3 * L_ + 16];
        s4 bf0 = pack4(b00, b01, b02, b03);
        s4 bf1 = pack4(b10, b11, b12, b13);

        acc0 = MFMA16(a, bf0, acc0);
        acc1 = MFMA16(a, bf1, acc1);
    }

    if (which == 2) {
        unsigned short* vp = Vt + ((size_t)bh * DK + q * 4) * L_ + n0 + m;
        vp[0]      = f2bf(acc0[0]); vp[L_]     = f2bf(acc0[1]);
        vp[2 * L_] = f2bf(acc0[2]); vp[3 * L_] = f2bf(acc0[3]);
        vp += 16;
        vp[0]      = f2bf(acc1[0]); vp[L_]     = f2bf(acc1[1]);
        vp[2 * L_] = f2bf(acc1[2]); vp[3 * L_] = f2bf(acc1[3]);
    } else {
        const float sc = (which == 1) ? 0.25f : 1.0f;
        unsigned short* T = (which == 0) ? Qt : Kt;
        uint2 u0, u1;
        u0.x = pack2(acc0[0] * sc, acc0[1] * sc);
        u0.y = pack2(acc0[2] * sc, acc0[3] * sc);
        u1.x = pack2(acc1[0] * sc, acc1[1] * sc);
        u1.y = pack2(acc1[2] * sc, acc1[3] * sc);
        *(uint2*)(T + ((size_t)bh * L_ + n0 + m) * DK + q * 4)      = u0;
        *(uint2*)(T + ((size_t)bh * L_ + n0 + 16 + m) * DK + q * 4) = u1;
    }
}

// ---------------------------------------------------------------------------
// Kernel 2: FUSED attention + output projection.  One block per (b, 32 cols).
// Phase 1: each wave handles 2 heads (wv, wv+4) x 2 j-tiles, sharing aq/av
//   loads across tiles; normalized head tile -> LDS hls[l_local][d] (bf16,
//   rows padded to 132 shorts).
// Phase 2: out[b][o][jblk..+31] = Wo[b] @ hls (B-operand straight from LDS).
// grid (32, 8), block 256.
// ---------------------------------------------------------------------------
__global__ __launch_bounds__(256)
void attn_out_kernel(const unsigned short* __restrict__ Qt,
                     const unsigned short* __restrict__ Kt,
                     const unsigned short* __restrict__ Vt,
                     const float* __restrict__ Wo,
                     float* __restrict__ out) {
    const int lane = threadIdx.x & 63;
    const int wv   = threadIdx.x >> 6;
    const int m = lane & 15, q = lane >> 4;
    const int b    = blockIdx.y;
    const int jblk = blockIdx.x * 32;

    __shared__ unsigned short hls[32][132];   // [l_local][d], 8.25 KB

    // ---- Phase 1: attention for heads wv and wv+4, columns jblk..jblk+31
#pragma unroll
    for (int hh = 0; hh < 2; ++hh) {
        const int h  = wv + hh * 4;
        const int bh = b * NH + h;

        s4 bk0 = *(const s4*)(Kt + ((size_t)bh * L_ + jblk + m) * DK + q * 4);
        s4 bk1 = *(const s4*)(Kt + ((size_t)bh * L_ + jblk + 16 + m) * DK + q * 4);

        f4 O0 = {0.f, 0.f, 0.f, 0.f}, O1 = {0.f, 0.f, 0.f, 0.f};
        float ls0 = 0.f, ls1 = 0.f;
        const unsigned short* qbase = Qt + (size_t)bh * L_ * DK + q * 4;
        const unsigned short* vbase = Vt + ((size_t)bh * DK + m) * L_ + q * 4;

#pragma unroll 4
        for (int i0 = 0; i0 < L_; i0 += 16) {
            s4 aq = *(const s4*)(qbase + (size_t)(i0 + m) * DK);
            s4 av = *(const s4*)(vbase + i0);

            f4 z = {0.f, 0.f, 0.f, 0.f};
            f4 S0 = MFMA16(aq, bk0, z);     // S[i0+q*4+r][jblk+m]
            f4 S1 = MFMA16(aq, bk1, z);     // S[i0+q*4+r][jblk+16+m]

            float p00 = __expf(S0[0]), p01 = __expf(S0[1]);
            float p02 = __expf(S0[2]), p03 = __expf(S0[3]);
            float p10 = __expf(S1[0]), p11 = __expf(S1[1]);
            float p12 = __expf(S1[2]), p13 = __expf(S1[3]);
            ls0 += (p00 + p01) + (p02 + p03);
            ls1 += (p10 + p11) + (p12 + p13);

            s4 pb0, pb1;
            pb0[0] = (short)f2bf(p00); pb0[1] = (short)f2bf(p01);
            pb0[2] = (short)f2bf(p02); pb0[3] = (short)f2bf(p03);
            pb1[0] = (short)f2bf(p10); pb1[1] = (short)f2bf(p11);
            pb1[2] = (short)f2bf(p12); pb1[3] = (short)f2bf(p13);

            O0 = MFMA16(av, pb0, O0);       // O[v=q*4+r][col] += V*P
            O1 = MFMA16(av, pb1, O1);
        }

        ls0 += __shfl_xor(ls0, 16, 64);
        ls0 += __shfl_xor(ls0, 32, 64);
        ls1 += __shfl_xor(ls1, 16, 64);
        ls1 += __shfl_xor(ls1, 32, 64);
        const float inv0 = 1.f / ls0, inv1 = 1.f / ls1;

        // head tile rows l_local = {m, 16+m}, cols d = h*16 + q*4 + r
        uint2 o0, o1;
        o0.x = pack2(O0[0] * inv0, O0[1] * inv0);
        o0.y = pack2(O0[2] * inv0, O0[3] * inv0);
        o1.x = pack2(O1[0] * inv1, O1[1] * inv1);
        o1.y = pack2(O1[2] * inv1, O1[3] * inv1);
        *(uint2*)&hls[m][h * 16 + q * 4]      = o0;
        *(uint2*)&hls[16 + m][h * 16 + q * 4] = o1;
    }

    __syncthreads();

    // ---- Phase 2: out[b][o0+q*4+r][jblk(+16)+m], 2 o-chunks per wave
#pragma unroll
    for (int t = 0; t < 2; ++t) {
        const int oc = wv * 2 + t;
        const int o0 = oc * 16;
        const float* Wrow = Wo + ((size_t)b * D_ + o0 + m) * D_;

        f4 acc0 = {0.f, 0.f, 0.f, 0.f}, acc1 = {0.f, 0.f, 0.f, 0.f};
#pragma unroll
        for (int kb = 0; kb < 8; ++kb) {
            const int k4 = kb * 16 + q * 4;
            float4 wf = *(const float4*)(Wrow + k4);
            s4 a  = pack4(wf.x, wf.y, wf.z, wf.w);
            s4 b0 = *(const s4*)&hls[m][k4];        // B[k][n=l] = hls[l][k]
            s4 b1 = *(const s4*)&hls[16 + m][k4];
            acc0 = MFMA16(a, b0, acc0);
            acc1 = MFMA16(a, b1, acc1);
        }

        float* op = out + ((size_t)b * D_ + o0 + q * 4) * L_ + jblk + m;
        op[0]      = acc0[0]; op[L_]     = acc0[1];
        op[2 * L_] = acc0[2]; op[3 * L_] = acc0[3];
        op += 16;
        op[0]      = acc1[0]; op[L_]     = acc1[1];
        op[2 * L_] = acc1[2]; op[3 * L_] = acc1[3];
    }
}

// ---------------------------------------------------------------------------
extern "C" void kernel_launch(void* const* d_in, const int* in_sizes, int n_in,
                              void* d_out, int out_size, void* d_ws, size_t ws_size,
                              hipStream_t stream) {
    const float* x  = (const float*)d_in[0];
    const float* Wq = (const float*)d_in[1];
    const float* Wk = (const float*)d_in[2];
    const float* Wv = (const float*)d_in[3];
    const float* Wo = (const float*)d_in[4];
    float* out = (float*)d_out;

    const size_t SEG = (size_t)B_ * NH * DK * L_;   // 1,048,576 elements
    unsigned short* Qt = (unsigned short*)d_ws;     // bf16 [bh][l][k], 2 MB
    unsigned short* Kt = Qt + SEG;                  // bf16 [bh][j][k], 2 MB
    unsigned short* Vt = Kt + SEG;                  // bf16 [bh][v][i], 2 MB

    proj_kernel<<<dim3(8, B_ * NH, 3), 256, 0, stream>>>(x, Wq, Wk, Wv, Qt, Kt, Vt);
    attn_out_kernel<<<dim3(32, B_), 256, 0, stream>>>(Qt, Kt, Vt, Wo, out);
}